// Round 6
// baseline (305.195 us; speedup 1.0000x reference)
//
#include <hip/hip_runtime.h>
#include <stdint.h>

#define M_DIM 8192
#define N_DIM 4096
#define K_DIM 4096
#define CBN   (K_DIM/8)   // 512 column groups per row
#define ITERS 32          // 64 K-tiles of BK=64, 2 per iteration

typedef __attribute__((ext_vector_type(8))) short bf16x8;
typedef __attribute__((ext_vector_type(8))) unsigned short u16x8;
typedef __attribute__((ext_vector_type(4))) float f32x4;

#define AS_GLOBAL(p) (const __attribute__((address_space(1))) void*)(p)
#define AS_LDS(p)    (__attribute__((address_space(3))) void*)(p)

static __device__ __forceinline__ unsigned short f2bf(float f) {
    union { float f; uint32_t u; } c; c.f = f;
    uint32_t u = c.u;
    return (unsigned short)((u + 0x7fffu + ((u >> 16) & 1u)) >> 16);
}

// ---------------------------------------------------------------------------
// Kernel 1: per (ob, cb) pick top-4 columns (of 8) by L1 mass over 64 rows.
// ---------------------------------------------------------------------------
__global__ __launch_bounds__(256) void venom_sel(const float* __restrict__ W,
                                                 uint16_t* __restrict__ sel) {
    int t   = threadIdx.x;
    int ob  = blockIdx.x;
    int col = blockIdx.y * 256 + t;
    const float* p = W + (size_t)(ob * 64) * K_DIM + col;
    double s = 0.0;
    #pragma unroll 16
    for (int r = 0; r < 64; ++r) s += fabsf(p[(size_t)r * K_DIM]);

    int lane = t & 63;
    int base = lane & ~7;
    double sc[8];
    #pragma unroll
    for (int j = 0; j < 8; ++j) sc[j] = __shfl(s, base + j, 64);

    uint32_t packed = 0;
    #pragma unroll
    for (int c = 0; c < 8; ++c) {
        int rank = 0;
        #pragma unroll
        for (int j = 0; j < 8; ++j)
            rank += (sc[j] > sc[c]) || (sc[j] == sc[c] && j < c);
        if (rank < 4) packed |= (uint32_t)c << (4 * rank);
    }
    if ((lane & 7) == 0) {
        int cb = col >> 3;
        sel[ob * CBN + cb] = (uint16_t)packed;
    }
}

// ---------------------------------------------------------------------------
// Kernel 2: masked bf16 weight pack (top-2 of selected 4 by |w|).
// ---------------------------------------------------------------------------
__global__ __launch_bounds__(256) void venom_pack(const float* __restrict__ W,
                                                  const uint16_t* __restrict__ sel,
                                                  unsigned short* __restrict__ Wb) {
    int gid = blockIdx.x * 256 + threadIdx.x;
    int o  = gid >> 9;
    int cb = gid & (CBN - 1);
    uint32_t pk = sel[(o >> 6) * CBN + cb];
    const float* p = W + (size_t)o * K_DIM + cb * 8;
    float4 a = *(const float4*)p;
    float4 b = *(const float4*)(p + 4);
    float w[8] = {a.x, a.y, a.z, a.w, b.x, b.y, b.z, b.w};

    int   c[4]; float v[4];
    #pragma unroll
    for (int pz = 0; pz < 4; ++pz) {
        c[pz] = (pk >> (4 * pz)) & 7;
        v[pz] = fabsf(w[c[pz]]);
    }
    uint32_t keep = 0;
    #pragma unroll
    for (int pz = 0; pz < 4; ++pz) {
        int cnt = 0;
        #pragma unroll
        for (int q = 0; q < 4; ++q)
            cnt += (v[q] > v[pz]) || (v[q] == v[pz] && q < pz);
        if (cnt < 2) keep |= 1u << c[pz];
    }
    u16x8 out;
    #pragma unroll
    for (int j = 0; j < 8; ++j)
        out[j] = f2bf(((keep >> j) & 1) ? w[j] : 0.0f);
    *(u16x8*)(Wb + (size_t)gid * 8) = out;
}

// ---------------------------------------------------------------------------
// Kernel 3: x f32 -> bf16 (RNE).
// ---------------------------------------------------------------------------
__global__ __launch_bounds__(256) void xcvt(const float* __restrict__ X,
                                            unsigned short* __restrict__ Xb) {
    size_t gid = (size_t)blockIdx.x * 256 + threadIdx.x;
    const float4* p = (const float4*)X + gid * 2;
    float4 a = p[0], b = p[1];
    float w[8] = {a.x, a.y, a.z, a.w, b.x, b.y, b.z, b.w};
    u16x8 out;
    #pragma unroll
    for (int j = 0; j < 8; ++j) out[j] = f2bf(w[j]);
    *(u16x8*)(Xb + gid * 8) = out;
}

// ---------------------------------------------------------------------------
// Kernel 4: 256x256 bf16 GEMM, 8-phase (round-3 phase structure: reads ->
// stage -> BAR -> lgkm(0) -> setprio+16 MFMA -> [CKPT] -> BAR), with staging
// DEEPENED to 3 groups in flight (m201's vmcnt(6)-analog):
//   stages: P1: t(2it+1).ks1->buf1.ks1   P3: t(2it+2).ks0->buf0.ks0
//           P5: t(2it+2).ks1->buf0.ks1   P7: t(2it+3).ks0->buf1.ks0
//   CKPT vmcnt(8) at end of every odd phase -> waits on loads issued 4 phases
//   (~640 cy) earlier; stage->first-read distance = 6 phases.
// Ledger (steady): R-after-W: P1top<-prev CKPT@P7(8); P3top<-CKPT@P1(8);
//   P5top<-CKPT@P3(8); P7top<-CKPT@P5(8). W-after-R: each overwritten
//   region's last read is 1 phase before the stage, drained by that phase's
//   lgkm(0) before its closing barrier.
// Tail (it=ITERS-1, stages P3/P5/P7 skipped): CKPT@P3=vmcnt(4) (drains
//   t63.ks0 staged P7-prev), CKPT@P5=vmcnt(0) (drains t63.ks1 staged P1),
//   CKPT@P7 dropped. Never vmcnt(0) in steady state.
// ---------------------------------------------------------------------------
__global__ __launch_bounds__(512, 2) void gemm256(const unsigned short* __restrict__ A,
                                                  const unsigned short* __restrict__ B,
                                                  const float* __restrict__ bias,
                                                  float* __restrict__ C) {
    __shared__ __align__(16) unsigned char smem[131072]; // A:[0,64K) B:[64K,128K)

    int t    = threadIdx.x;
    int wid  = t >> 6;
    int lane = t & 63;
    int l16  = lane & 15;
    int lk   = lane >> 4;
    int wm   = wid >> 2;     // wave row-half (128 rows)
    int wn   = wid & 3;      // wave col-quarter (64 cols)

    // XCD-aware bijective swizzle (512 blocks % 8 == 0)
    int bid = blockIdx.x;
    int swz = (bid & 7) * ((int)gridDim.x >> 3) + (bid >> 3);
    int bm  = swz >> 4;
    int bn  = swz & 15;

    // staging: thread t covers row r=t>>2 (and r+128), phys chunk t&3 holds
    // logical chunk (t&3)^((r>>1)&3) = (t&3)^((t>>3)&3)
    int gch = ((t & 3) ^ ((t >> 3) & 3)) * 8;
    const unsigned short* agbase = A + (size_t)(bm * 256 + (t >> 2)) * K_DIM + gch;
    const unsigned short* bgbase = B + (size_t)(bn * 256 + (t >> 2)) * K_DIM + gch;

    auto stageAB = [&](int tile, int ks, int buf) {
        const unsigned short* ga = agbase + tile * 64 + ks * 32;
        const unsigned short* gb = bgbase + tile * 64 + ks * 32;
        char* la = (char*)smem + buf * 32768 + ks * 16384 + wid * 1024;
        char* lb = la + 65536;
        __builtin_amdgcn_global_load_lds(AS_GLOBAL(ga), AS_LDS(la), 16, 0, 0);
        __builtin_amdgcn_global_load_lds(AS_GLOBAL(ga + (size_t)128 * K_DIM), AS_LDS(la + 8192), 16, 0, 0);
        __builtin_amdgcn_global_load_lds(AS_GLOBAL(gb), AS_LDS(lb), 16, 0, 0);
        __builtin_amdgcn_global_load_lds(AS_GLOBAL(gb + (size_t)128 * K_DIM), AS_LDS(lb + 8192), 16, 0, 0);
    };

    // read-side: row R = base+l16, k-chunk lk -> phys chunk lk^((l16>>1)&3)
    int koff = ((lk ^ ((l16 >> 1) & 3)) << 4);
    const char* ardb = (const char*)smem + (wm * 128 + l16) * 64 + koff;
    const char* brdb = (const char*)smem + 65536 + (wn * 64 + l16) * 64 + koff;

    f32x4 acc[8][4] = {};
    bf16x8 af[4], bfr[4];

#define PH_READS(BUF, KS, MH, LOADB)                                               \
    if (LOADB) {                                                                   \
        _Pragma("unroll")                                                          \
        for (int g = 0; g < 4; ++g)                                                \
            bfr[g] = *(const bf16x8*)(brdb + (BUF)*32768 + (KS)*16384 + g * 1024); \
    }                                                                              \
    _Pragma("unroll")                                                              \
    for (int i = 0; i < 4; ++i)                                                    \
        af[i] = *(const bf16x8*)(ardb + (BUF)*32768 + (KS)*16384 + ((MH)*4 + i) * 1024);

#define PH_EXEC(MH)                                                                \
    __builtin_amdgcn_s_barrier();                                                  \
    asm volatile("s_waitcnt lgkmcnt(0)" ::: "memory");                             \
    __builtin_amdgcn_sched_barrier(0);                                             \
    __builtin_amdgcn_s_setprio(1);                                                 \
    _Pragma("unroll")                                                              \
    for (int i = 0; i < 4; ++i)                                                    \
        _Pragma("unroll")                                                          \
        for (int g = 0; g < 4; ++g)                                                \
            acc[(MH)*4 + i][g] = __builtin_amdgcn_mfma_f32_16x16x32_bf16(af[i], bfr[g], acc[(MH)*4 + i][g], 0, 0, 0); \
    __builtin_amdgcn_s_setprio(0);                                                 \
    __builtin_amdgcn_sched_barrier(0);

#define PH_CLOSE()                                                                 \
    __builtin_amdgcn_s_barrier();                                                  \
    __builtin_amdgcn_sched_barrier(0);

#define CKPT8()  { asm volatile("s_waitcnt vmcnt(8)" ::: "memory"); __builtin_amdgcn_sched_barrier(0); }
#define CKPT4()  { asm volatile("s_waitcnt vmcnt(4)" ::: "memory"); __builtin_amdgcn_sched_barrier(0); }
#define CKPT0()  { asm volatile("s_waitcnt vmcnt(0)" ::: "memory"); __builtin_amdgcn_sched_barrier(0); }

    // prologue: 3 stage groups in flight; drain group 1 (t0.ks0) only
    stageAB(0, 0, 0);
    stageAB(0, 1, 0);
    stageAB(1, 0, 1);
    CKPT8()
    __builtin_amdgcn_s_barrier();
    __builtin_amdgcn_sched_barrier(0);

    for (int it = 0; it < ITERS; ++it) {
        bool more = (it < ITERS - 1);

        // P1: compute t(2it).ks0 Mh0 | stage t(2it+1).ks1 -> buf1.ks1
        PH_READS(0, 0, 0, 1)
        stageAB(2 * it + 1, 1, 1);
        PH_EXEC(0)
        CKPT8()
        PH_CLOSE()
        // P2: Mh1
        PH_READS(0, 0, 1, 0)
        PH_EXEC(1)
        PH_CLOSE()
        // P3: t(2it).ks1 Mh0 | stage t(2it+2).ks0 -> buf0.ks0
        PH_READS(0, 1, 0, 1)
        if (more) stageAB(2 * it + 2, 0, 0);
        PH_EXEC(0)
        if (more) { CKPT8() } else { CKPT4() }
        PH_CLOSE()
        // P4: Mh1
        PH_READS(0, 1, 1, 0)
        PH_EXEC(1)
        PH_CLOSE()
        // P5: t(2it+1).ks0 Mh0 | stage t(2it+2).ks1 -> buf0.ks1
        PH_READS(1, 0, 0, 1)
        if (more) stageAB(2 * it + 2, 1, 0);
        PH_EXEC(0)
        if (more) { CKPT8() } else { CKPT0() }
        PH_CLOSE()
        // P6: Mh1
        PH_READS(1, 0, 1, 0)
        PH_EXEC(1)
        PH_CLOSE()
        // P7: t(2it+1).ks1 Mh0 | stage t(2it+3).ks0 -> buf1.ks0
        PH_READS(1, 1, 0, 1)
        if (more) stageAB(2 * it + 3, 0, 1);
        PH_EXEC(0)
        if (more) { CKPT8() }
        PH_CLOSE()
        // P8: Mh1
        PH_READS(1, 1, 1, 0)
        PH_EXEC(1)
        PH_CLOSE()
    }

    // epilogue: C/D layout col = lane&15, row = (lane>>4)*4 + reg
    int    colb = bn * 256 + wn * 64;
    size_t rowb = (size_t)bm * 256 + wm * 128 + (lk << 2);
    #pragma unroll
    for (int g = 0; g < 4; ++g) {
        int col = colb + g * 16 + l16;
        float bv = bias[col];
        #pragma unroll
        for (int f = 0; f < 8; ++f) {
            size_t r0 = rowb + f * 16;
            #pragma unroll
            for (int rg = 0; rg < 4; ++rg)
                C[(r0 + rg) * N_DIM + col] = acc[f][g][rg] + bv;
        }
    }
}

extern "C" void kernel_launch(void* const* d_in, const int* in_sizes, int n_in,
                              void* d_out, int out_size, void* d_ws, size_t ws_size,
                              hipStream_t stream) {
    const float* x    = (const float*)d_in[0];
    const float* W    = (const float*)d_in[1];
    const float* bias = (const float*)d_in[2];
    float* out = (float*)d_out;

    char* ws = (char*)d_ws;
    unsigned short* xb  = (unsigned short*)ws;                                   // 64 MB
    unsigned short* wb  = (unsigned short*)(ws + (size_t)M_DIM * K_DIM * 2);     // 32 MB
    uint16_t*       sel = (uint16_t*)(ws + (size_t)M_DIM * K_DIM * 2
                                         + (size_t)N_DIM * K_DIM * 2);           // 64 KB

    venom_sel <<<dim3(64, 16), 256, 0, stream>>>(W, sel);
    venom_pack<<<dim3((N_DIM * CBN) / 256), 256, 0, stream>>>(W, sel, wb);
    xcvt      <<<dim3((M_DIM * K_DIM / 8) / 256), 256, 0, stream>>>(x, xb);
    gemm256   <<<dim3((M_DIM / 256) * (N_DIM / 256)), 512, 0, stream>>>(xb, wb, bias, out);
}

// Round 7
// 289.585 us; speedup vs baseline: 1.0539x; 1.0539x over previous
//
#include <hip/hip_runtime.h>
#include <stdint.h>

#define M_DIM 8192
#define N_DIM 4096
#define K_DIM 4096
#define CBN   (K_DIM/8)   // 512 column groups per row

typedef __attribute__((ext_vector_type(8))) short bf16x8;
typedef __attribute__((ext_vector_type(8))) unsigned short u16x8;
typedef __attribute__((ext_vector_type(4))) float f32x4;

#define AS_GLOBAL(p) (const __attribute__((address_space(1))) void*)(p)
#define AS_LDS(p)    (__attribute__((address_space(3))) void*)(p)

static __device__ __forceinline__ unsigned short f2bf(float f) {
    union { float f; uint32_t u; } c; c.f = f;
    uint32_t u = c.u;
    return (unsigned short)((u + 0x7fffu + ((u >> 16) & 1u)) >> 16);
}

// ---------------------------------------------------------------------------
// Kernel 1: per (ob, cb) pick top-4 columns (of 8) by L1 mass over 64 rows.
// ---------------------------------------------------------------------------
__global__ __launch_bounds__(256) void venom_sel(const float* __restrict__ W,
                                                 uint16_t* __restrict__ sel) {
    int t   = threadIdx.x;
    int ob  = blockIdx.x;
    int col = blockIdx.y * 256 + t;
    const float* p = W + (size_t)(ob * 64) * K_DIM + col;
    double s = 0.0;
    #pragma unroll 16
    for (int r = 0; r < 64; ++r) s += fabsf(p[(size_t)r * K_DIM]);

    int lane = t & 63;
    int base = lane & ~7;
    double sc[8];
    #pragma unroll
    for (int j = 0; j < 8; ++j) sc[j] = __shfl(s, base + j, 64);

    uint32_t packed = 0;
    #pragma unroll
    for (int c = 0; c < 8; ++c) {
        int rank = 0;
        #pragma unroll
        for (int j = 0; j < 8; ++j)
            rank += (sc[j] > sc[c]) || (sc[j] == sc[c] && j < c);
        if (rank < 4) packed |= (uint32_t)c << (4 * rank);
    }
    if ((lane & 7) == 0) {
        int cb = col >> 3;
        sel[ob * CBN + cb] = (uint16_t)packed;
    }
}

// ---------------------------------------------------------------------------
// Kernel 2: masked bf16 weight pack (top-2 of selected 4 by |w|).
// ---------------------------------------------------------------------------
__global__ __launch_bounds__(256) void venom_pack(const float* __restrict__ W,
                                                  const uint16_t* __restrict__ sel,
                                                  unsigned short* __restrict__ Wb) {
    int gid = blockIdx.x * 256 + threadIdx.x;
    int o  = gid >> 9;
    int cb = gid & (CBN - 1);
    uint32_t pk = sel[(o >> 6) * CBN + cb];
    const float* p = W + (size_t)o * K_DIM + cb * 8;
    float4 a = *(const float4*)p;
    float4 b = *(const float4*)(p + 4);
    float w[8] = {a.x, a.y, a.z, a.w, b.x, b.y, b.z, b.w};

    int   c[4]; float v[4];
    #pragma unroll
    for (int pz = 0; pz < 4; ++pz) {
        c[pz] = (pk >> (4 * pz)) & 7;
        v[pz] = fabsf(w[c[pz]]);
    }
    uint32_t keep = 0;
    #pragma unroll
    for (int pz = 0; pz < 4; ++pz) {
        int cnt = 0;
        #pragma unroll
        for (int q = 0; q < 4; ++q)
            cnt += (v[q] > v[pz]) || (v[q] == v[pz] && q < pz);
        if (cnt < 2) keep |= 1u << c[pz];
    }
    u16x8 out;
    #pragma unroll
    for (int j = 0; j < 8; ++j)
        out[j] = f2bf(((keep >> j) & 1) ? w[j] : 0.0f);
    *(u16x8*)(Wb + (size_t)gid * 8) = out;
}

// ---------------------------------------------------------------------------
// Kernel 3: x f32 -> bf16 (RNE).
// ---------------------------------------------------------------------------
__global__ __launch_bounds__(256) void xcvt(const float* __restrict__ X,
                                            unsigned short* __restrict__ Xb) {
    size_t gid = (size_t)blockIdx.x * 256 + threadIdx.x;
    const float4* p = (const float4*)X + gid * 2;
    float4 a = p[0], b = p[1];
    float w[8] = {a.x, a.y, a.z, a.w, b.x, b.y, b.z, b.w};
    u16x8 out;
    #pragma unroll
    for (int j = 0; j < 8; ++j) out[j] = f2bf(w[j]);
    *(u16x8*)(Xb + gid * 8) = out;
}

// ---------------------------------------------------------------------------
// Kernel 4: 256x256 bf16 GEMM. Super-phase schedule, ONE barrier per
// super-phase (4/iter; round 3 had 16/iter). SP_s (slice s = 32-k-chunk):
//   { 12 ds_read (bfr, af0, af1) | stageA(s+2) | lgkm(4) | 16 MFMA Mh0 |
//     stageB(s+2) | lgkm(0) | 16 MFMA Mh1 | vmcnt(4) | s_barrier }
// No opening barrier -> waves desync inside the SP, LDS-pipe drain overlaps
// the other waves' MFMA (round-3's convoy serialized them: 49% MfmaUtil).
// Slice s lives in buf[(s>>1)&1], ks=(s&1): 4 resident 32KB slice-regions.
// Ledger (uniform): SP_s stages slice s+2; CKPT@s = vmcnt(4) drains stage@s-1
//   (outstanding = stage(s-1)+stage(s) = 8) -> read@s+1 is covered by
//   CKPT@s + BAR@s. W-after-R: stage@s overwrites the region read @s-4;
//   readers' lgkm(0) precedes >=2 closing barriers before the stage issue.
// Tail: SP126 has no stage -> vmcnt(0) (drains stage@125 for read@127);
//   SP127: no CKPT (lgkm(0) guards its MFMAs). Prologue stages slices 0,1;
//   vmcnt(4) drains slice0; BAR.
// ---------------------------------------------------------------------------
__global__ __launch_bounds__(512, 2) void gemm256(const unsigned short* __restrict__ A,
                                                  const unsigned short* __restrict__ B,
                                                  const float* __restrict__ bias,
                                                  float* __restrict__ C) {
    __shared__ __align__(16) unsigned char smem[131072]; // A:[0,64K) B:[64K,128K)

    int t    = threadIdx.x;
    int wid  = t >> 6;
    int lane = t & 63;
    int l16  = lane & 15;
    int lk   = lane >> 4;
    int wm   = wid >> 2;     // wave row-half (128 rows)
    int wn   = wid & 3;      // wave col-quarter (64 cols)

    // XCD-aware bijective swizzle (512 blocks % 8 == 0)
    int bid = blockIdx.x;
    int swz = (bid & 7) * ((int)gridDim.x >> 3) + (bid >> 3);
    int bm  = swz >> 4;
    int bn  = swz & 15;

    // staging: thread t covers row r=t>>2 (and r+128), phys chunk t&3 holds
    // logical chunk (t&3)^((r>>1)&3) = (t&3)^((t>>3)&3)
    int gch = ((t & 3) ^ ((t >> 3) & 3)) * 8;
    const unsigned short* agbase = A + (size_t)(bm * 256 + (t >> 2)) * K_DIM + gch;
    const unsigned short* bgbase = B + (size_t)(bn * 256 + (t >> 2)) * K_DIM + gch;

    auto stageA2 = [&](int slice, int bufp) {
        const unsigned short* ga = agbase + slice * 32;
        char* la = (char*)smem + bufp * 32768 + (slice & 1) * 16384 + wid * 1024;
        __builtin_amdgcn_global_load_lds(AS_GLOBAL(ga), AS_LDS(la), 16, 0, 0);
        __builtin_amdgcn_global_load_lds(AS_GLOBAL(ga + (size_t)128 * K_DIM), AS_LDS(la + 8192), 16, 0, 0);
    };
    auto stageB2 = [&](int slice, int bufp) {
        const unsigned short* gb = bgbase + slice * 32;
        char* lb = (char*)smem + 65536 + bufp * 32768 + (slice & 1) * 16384 + wid * 1024;
        __builtin_amdgcn_global_load_lds(AS_GLOBAL(gb), AS_LDS(lb), 16, 0, 0);
        __builtin_amdgcn_global_load_lds(AS_GLOBAL(gb + (size_t)128 * K_DIM), AS_LDS(lb + 8192), 16, 0, 0);
    };

    // read-side: row R = base+l16, k-chunk lk -> phys chunk lk^((l16>>1)&3)
    int koff = ((lk ^ ((l16 >> 1) & 3)) << 4);
    const char* ardb = (const char*)smem + (wm * 128 + l16) * 64 + koff;
    const char* brdb = (const char*)smem + 65536 + (wn * 64 + l16) * 64 + koff;

    f32x4 acc[8][4] = {};
    bf16x8 af0[4], af1[4], bfr[4];

#define LGKM(N) { asm volatile("s_waitcnt lgkmcnt(" #N ")" ::: "memory");            \
                  __builtin_amdgcn_sched_barrier(0); }
#define CKPT4() { asm volatile("s_waitcnt vmcnt(4)" ::: "memory");                   \
                  __builtin_amdgcn_sched_barrier(0); }
#define CKPT0() { asm volatile("s_waitcnt vmcnt(0)" ::: "memory");                   \
                  __builtin_amdgcn_sched_barrier(0); }
#define BAR()   { __builtin_amdgcn_s_barrier(); __builtin_amdgcn_sched_barrier(0); }

    // SP body. P: resident buf (runtime 0/1). K: ks. SS: slice staged (s+2).
    // DOSTAGE: 0 none. CK: 0 none, 4 vmcnt(4), 1 vmcnt(0).
#define SP(P, K, SS, DOSTAGE, CK)                                                    \
    {                                                                                \
        const char* abase = ardb + (P) * 32768 + (K) * 16384;                        \
        const char* bbase = brdb + (P) * 32768 + (K) * 16384;                        \
        _Pragma("unroll")                                                            \
        for (int g = 0; g < 4; ++g) bfr[g] = *(const bf16x8*)(bbase + g * 1024);     \
        _Pragma("unroll")                                                            \
        for (int i = 0; i < 4; ++i) af0[i] = *(const bf16x8*)(abase + i * 1024);     \
        _Pragma("unroll")                                                            \
        for (int i = 0; i < 4; ++i) af1[i] = *(const bf16x8*)(abase + (4+i) * 1024); \
        if (DOSTAGE) stageA2((SS), (P) ^ 1);                                         \
        LGKM(4)                                                                      \
        __builtin_amdgcn_s_setprio(1);                                               \
        _Pragma("unroll")                                                            \
        for (int i = 0; i < 4; ++i)                                                  \
            _Pragma("unroll")                                                        \
            for (int g = 0; g < 4; ++g)                                              \
                acc[i][g] = __builtin_amdgcn_mfma_f32_16x16x32_bf16(af0[i], bfr[g], acc[i][g], 0, 0, 0); \
        __builtin_amdgcn_s_setprio(0);                                               \
        __builtin_amdgcn_sched_barrier(0);                                           \
        if (DOSTAGE) stageB2((SS), (P) ^ 1);                                         \
        LGKM(0)                                                                      \
        __builtin_amdgcn_s_setprio(1);                                               \
        _Pragma("unroll")                                                            \
        for (int i = 0; i < 4; ++i)                                                  \
            _Pragma("unroll")                                                        \
            for (int g = 0; g < 4; ++g)                                              \
                acc[4+i][g] = __builtin_amdgcn_mfma_f32_16x16x32_bf16(af1[i], bfr[g], acc[4+i][g], 0, 0, 0); \
        __builtin_amdgcn_s_setprio(0);                                               \
        __builtin_amdgcn_sched_barrier(0);                                           \
        if ((CK) == 4) { CKPT4() } else if ((CK) == 1) { CKPT0() }                   \
        BAR()                                                                        \
    }

    // prologue: slices 0,1 -> buf0; drain slice0's 4 loads; sync
    stageA2(0, 0); stageB2(0, 0);
    stageA2(1, 0); stageB2(1, 0);
    CKPT4()
    BAR()

    for (int it = 0; it < 63; ++it) {
        int p = it & 1;
        SP(p, 0, 2 * (it + 1) + 0, 1, 4)   // slice 2it,   stage 2it+2
        SP(p, 1, 2 * (it + 1) + 1, 1, 4)   // slice 2it+1, stage 2it+3
    }
    // it = 63 (p = 1): slices 126, 127 — no stages
    SP(1, 0, 0, 0, 1)                      // vmcnt(0): drain stage@125 for 127
    SP(1, 1, 0, 0, 0)

    // epilogue: C/D layout col = lane&15, row = (lane>>4)*4 + reg
    int    colb = bn * 256 + wn * 64;
    size_t rowb = (size_t)bm * 256 + wm * 128 + (lk << 2);
    #pragma unroll
    for (int g = 0; g < 4; ++g) {
        int col = colb + g * 16 + l16;
        float bv = bias[col];
        #pragma unroll
        for (int f = 0; f < 8; ++f) {
            size_t r0 = rowb + f * 16;
            #pragma unroll
            for (int rg = 0; rg < 4; ++rg)
                C[(r0 + rg) * N_DIM + col] = acc[f][g][rg] + bv;
        }
    }
}

extern "C" void kernel_launch(void* const* d_in, const int* in_sizes, int n_in,
                              void* d_out, int out_size, void* d_ws, size_t ws_size,
                              hipStream_t stream) {
    const float* x    = (const float*)d_in[0];
    const float* W    = (const float*)d_in[1];
    const float* bias = (const float*)d_in[2];
    float* out = (float*)d_out;

    char* ws = (char*)d_ws;
    unsigned short* xb  = (unsigned short*)ws;                                   // 64 MB
    unsigned short* wb  = (unsigned short*)(ws + (size_t)M_DIM * K_DIM * 2);     // 32 MB
    uint16_t*       sel = (uint16_t*)(ws + (size_t)M_DIM * K_DIM * 2
                                         + (size_t)N_DIM * K_DIM * 2);           // 64 KB

    venom_sel <<<dim3(64, 16), 256, 0, stream>>>(W, sel);
    venom_pack<<<dim3((N_DIM * CBN) / 256), 256, 0, stream>>>(W, sel, wb);
    xcvt      <<<dim3((M_DIM * K_DIM / 8) / 256), 256, 0, stream>>>(x, xb);
    gemm256   <<<dim3((M_DIM / 256) * (N_DIM / 256)), 512, 0, stream>>>(xb, wb, bias, out);
}